// Round 2
// baseline (2332.877 us; speedup 1.0000x reference)
//
#include <hip/hip_runtime.h>
#include <cstdint>

// ---------------------------------------------------------------------------
// JukeboxAutoEncoder: fp32 implementation, round 2.
// Layout: all activations (B, T, C=64), C contiguous.
// Output layout (flat f32): x_hat[262144] | loss_vq[1] | ids[32768] | sim[16777216]
// Round-2 changes:
//  - VQ split into barrier-free vq_dots (per-wave shuffle argmin, sim writes)
//    + vq_finish (cross-wave argmin, z_q gather, per-block loss partials)
//    + loss_fin reduction. No __syncthreads in the hot VQ path, no atomics.
//  - conv3 retiled to 128 outputs/block (8 t per thread, acc[8][4]): halves
//    barrier+staging overhead per FMA. LDS ~50KB -> 3 blocks/CU.
// ---------------------------------------------------------------------------

#define OFF_LOSS 262144
#define OFF_IDS  262145
#define OFF_SIM  294913

// ---------------- down0: (B,65536,1) -> (B,32768,64), K=4 stride2, relu ----
__global__ __launch_bounds__(256) void down0_kernel(
    const float* __restrict__ x, const float* __restrict__ w,
    const float* __restrict__ bias, float* __restrict__ y)
{
  int idx = blockIdx.x * 256 + threadIdx.x;   // enumerates (b, t, co)
  int co = idx & 63;
  int r  = idx >> 6;
  int t  = r & 32767;
  int b  = r >> 15;
  const float* xb = x + (size_t)b * 65536;
  float acc = bias[co];
  #pragma unroll
  for (int k = 0; k < 4; ++k) {
    int gt = 2 * t - 1 + k;
    float xv = ((unsigned)gt < 65536u) ? xb[gt] : 0.f;
    acc += xv * w[k * 64 + co];
  }
  y[(size_t)idx] = fmaxf(acc, 0.f);
}

// ---------------- conv3: K=3, dilation DIL, 64->64, relu, optional +res ----
// 128 outputs per block; y = (HAS_RES ? res : 0) + relu(conv(x) + bias)
template <int DIL, bool HAS_RES>
__global__ __launch_bounds__(256) void conv3_kernel(
    const float* __restrict__ x, const float* __restrict__ w,
    const float* __restrict__ bias, const float* res,
    float* y, int T)
{
  constexpr int TT = 128;
  constexpr int XT = TT + 2 * DIL;
  constexpr int XS = XT + 1;                 // odd stride -> conflict-free
  __shared__ float xs[64 * XS];
  __shared__ float wsm[4096];                // one k-slice: 64x64
  const int tid = threadIdx.x;
  const int b   = blockIdx.y;
  const int t0  = blockIdx.x * TT;

  for (int e = tid; e < 64 * XT; e += 256) { // transpose to [ci][t]
    int tl = e >> 6, ci = e & 63;
    int gt = t0 - DIL + tl;
    float v = 0.f;
    if ((unsigned)gt < (unsigned)T) v = x[((size_t)b * T + gt) * 64 + ci];
    xs[ci * XS + tl] = v;
  }

  const int co = (tid & 15) * 4;
  const int tb = (tid >> 4) * 8;
  float acc[8][4] = {};

  for (int k = 0; k < 3; ++k) {
    __syncthreads();
    {
      const float4* src = (const float4*)(w + (size_t)k * 4096);
      float4* dst = (float4*)wsm;
      for (int i = tid; i < 1024; i += 256) dst[i] = src[i];
    }
    __syncthreads();
    const float* xk = xs + tb + k * DIL;
    #pragma unroll 4
    for (int ci = 0; ci < 64; ++ci) {
      float4 wv = *(const float4*)&wsm[ci * 64 + co];
      const float* xr = xk + ci * XS;
      #pragma unroll
      for (int i = 0; i < 8; ++i) {
        float xv = xr[i];
        acc[i][0] += xv * wv.x; acc[i][1] += xv * wv.y;
        acc[i][2] += xv * wv.z; acc[i][3] += xv * wv.w;
      }
    }
  }

  float4 bv = *(const float4*)&bias[co];
  #pragma unroll
  for (int i = 0; i < 8; ++i) {
    size_t o = ((size_t)b * T + t0 + tb + i) * 64 + co;
    float4 rr;
    rr.x = fmaxf(acc[i][0] + bv.x, 0.f);
    rr.y = fmaxf(acc[i][1] + bv.y, 0.f);
    rr.z = fmaxf(acc[i][2] + bv.z, 0.f);
    rr.w = fmaxf(acc[i][3] + bv.w, 0.f);
    if (HAS_RES) {
      float4 rv = *(const float4*)&res[o];
      rr.x += rv.x; rr.y += rv.y; rr.z += rv.z; rr.w += rv.w;
    }
    *(float4*)&y[o] = rr;
  }
}

// ---------------- down2: K=4 stride2, 64->64, relu ------------------------
__global__ __launch_bounds__(256) void down2_kernel(
    const float* __restrict__ x, const float* __restrict__ w,
    const float* __restrict__ bias, float* __restrict__ y, int Tin)
{
  constexpr int XT = 130, XS = 131;
  __shared__ float xs[64 * XS];
  __shared__ float wsm[4096];
  const int tid = threadIdx.x;
  const int b   = blockIdx.y;
  const int t0  = blockIdx.x * 64;
  const int Tout = Tin >> 1;

  for (int e = tid; e < 64 * XT; e += 256) {
    int tl = e >> 6, ci = e & 63;
    int gt = 2 * t0 - 1 + tl;
    float v = 0.f;
    if ((unsigned)gt < (unsigned)Tin) v = x[((size_t)b * Tin + gt) * 64 + ci];
    xs[ci * XS + tl] = v;
  }

  const int co = (tid & 15) * 4;
  const int tb = (tid >> 4) * 4;
  float acc[4][4] = {};

  for (int k = 0; k < 4; ++k) {
    __syncthreads();
    {
      const float4* src = (const float4*)(w + (size_t)k * 4096);
      float4* dst = (float4*)wsm;
      for (int i = tid; i < 1024; i += 256) dst[i] = src[i];
    }
    __syncthreads();
    const float* xk = xs + 2 * tb + k;
    #pragma unroll 8
    for (int ci = 0; ci < 64; ++ci) {
      float4 wv = *(const float4*)&wsm[ci * 64 + co];
      float x0 = xk[ci * XS + 0];
      float x1 = xk[ci * XS + 2];
      float x2 = xk[ci * XS + 4];
      float x3 = xk[ci * XS + 6];
      acc[0][0] += x0 * wv.x; acc[0][1] += x0 * wv.y; acc[0][2] += x0 * wv.z; acc[0][3] += x0 * wv.w;
      acc[1][0] += x1 * wv.x; acc[1][1] += x1 * wv.y; acc[1][2] += x1 * wv.z; acc[1][3] += x1 * wv.w;
      acc[2][0] += x2 * wv.x; acc[2][1] += x2 * wv.y; acc[2][2] += x2 * wv.z; acc[2][3] += x2 * wv.w;
      acc[3][0] += x3 * wv.x; acc[3][1] += x3 * wv.y; acc[3][2] += x3 * wv.z; acc[3][3] += x3 * wv.w;
    }
  }

  float4 bv = *(const float4*)&bias[co];
  #pragma unroll
  for (int i = 0; i < 4; ++i) {
    size_t o = ((size_t)b * Tout + t0 + tb + i) * 64 + co;
    float4 rr;
    rr.x = fmaxf(acc[i][0] + bv.x, 0.f);
    rr.y = fmaxf(acc[i][1] + bv.y, 0.f);
    rr.z = fmaxf(acc[i][2] + bv.z, 0.f);
    rr.w = fmaxf(acc[i][3] + bv.w, 0.f);
    *(float4*)&y[o] = rr;
  }
}

// ---------------- up: conv_transpose K=4 stride2, 64->64, relu ------------
// y[2u]   = relu(b + w0^T x[u-1] + w2^T x[u])
// y[2u+1] = relu(b + w1^T x[u]   + w3^T x[u+1])
__global__ __launch_bounds__(256) void up_kernel(
    const float* __restrict__ x, const float* __restrict__ w,
    const float* __restrict__ bias, float* __restrict__ y, int Tin)
{
  constexpr int XT = 34, XS = 35;
  __shared__ float xs[64 * XS];
  __shared__ float wsm[4096];
  const int tid = threadIdx.x;
  const int b   = blockIdx.y;
  const int t0  = blockIdx.x * 64;
  const int u0  = t0 >> 1;
  const int Tout = Tin << 1;

  for (int e = tid; e < 64 * XT; e += 256) {
    int ul = e >> 6, ci = e & 63;
    int gu = u0 - 1 + ul;
    float v = 0.f;
    if ((unsigned)gu < (unsigned)Tin) v = x[((size_t)b * Tin + gu) * 64 + ci];
    xs[ci * XS + ul] = v;
  }

  const int co = (tid & 15) * 4;
  const int tb = (tid >> 4) * 4;
  const int ub = tb >> 1;
  float acc[4][4] = {};

  #pragma unroll
  for (int k = 0; k < 4; ++k) {
    __syncthreads();
    {
      const float4* src = (const float4*)(w + (size_t)k * 4096);
      float4* dst = (float4*)wsm;
      for (int i = tid; i < 1024; i += 256) dst[i] = src[i];
    }
    __syncthreads();
    const int base = (k + 1) >> 1;  // 0,1,1,2
    const int p = k & 1;            // parity row
    #pragma unroll 8
    for (int ci = 0; ci < 64; ++ci) {
      float4 wv = *(const float4*)&wsm[ci * 64 + co];
      float xa = xs[ci * XS + ub + base];
      float xb2 = xs[ci * XS + ub + base + 1];
      acc[p][0]   += xa * wv.x;  acc[p][1]   += xa * wv.y;  acc[p][2]   += xa * wv.z;  acc[p][3]   += xa * wv.w;
      acc[p+2][0] += xb2 * wv.x; acc[p+2][1] += xb2 * wv.y; acc[p+2][2] += xb2 * wv.z; acc[p+2][3] += xb2 * wv.w;
    }
  }

  float4 bv = *(const float4*)&bias[co];
  #pragma unroll
  for (int i = 0; i < 4; ++i) {
    size_t o = ((size_t)b * Tout + t0 + tb + i) * 64 + co;
    float4 rr;
    rr.x = fmaxf(acc[i][0] + bv.x, 0.f);
    rr.y = fmaxf(acc[i][1] + bv.y, 0.f);
    rr.z = fmaxf(acc[i][2] + bv.z, 0.f);
    rr.w = fmaxf(acc[i][3] + bv.w, 0.f);
    *(float4*)&y[o] = rr;
  }
}

// ---------------- proj: K=3 dil1, 64->1, linear ---------------------------
__global__ __launch_bounds__(256) void proj_kernel(
    const float* __restrict__ x, const float* __restrict__ w,
    const float* __restrict__ bias, float* __restrict__ out)
{
  const int lane = threadIdx.x & 63;
  const int wid  = (blockIdx.x * 256 + threadIdx.x) >> 6;  // 4096 waves
  const float w0 = w[lane], w1 = w[64 + lane], w2 = w[128 + lane];
  const float bb = bias[0];
  size_t base = (size_t)wid * 64;
  for (int i = 0; i < 64; ++i) {
    size_t tau = base + i;
    int b = (int)(tau >> 16);
    int t = (int)(tau & 65535);
    const float* xb = x + ((size_t)b * 65536) * 64;
    float pm = (t > 0)     ? xb[(size_t)(t - 1) * 64 + lane] : 0.f;
    float pc =               xb[(size_t)t * 64 + lane];
    float pp = (t < 65535) ? xb[(size_t)(t + 1) * 64 + lane] : 0.f;
    float s = pm * w0 + pc * w1 + pp * w2;
    #pragma unroll
    for (int off = 32; off; off >>= 1) s += __shfl_down(s, off);
    if (lane == 0) out[tau] = s + bb;
  }
}

// ---------------- nz: per-token sum of squares ----------------------------
__global__ __launch_bounds__(256) void nz_kernel(
    const float* __restrict__ ze, float* __restrict__ nz)
{
  int lane = threadIdx.x & 63;
  int tok  = (blockIdx.x * 256 + threadIdx.x) >> 6;  // 32768 waves
  float v = ze[(size_t)tok * 64 + lane];
  float s = v * v;
  #pragma unroll
  for (int off = 32; off; off >>= 1) s += __shfl_down(s, off);
  if (lane == 0) nz[tok] = s;
}

// ---------------- vq_dots: dists + sim + per-wave argmin (no barriers) ----
#define VQA_TOKS 32
__global__ __launch_bounds__(256) void vq_dots_kernel(
    const float* __restrict__ ze, const float* __restrict__ cb,
    const float* __restrict__ nzbuf, float* __restrict__ sim_out,
    float2* __restrict__ pmin)
{
  const int tid = threadIdx.x;
  const int c0 = tid, c1 = tid + 256;
  float r0[64], r1[64];
  #pragma unroll
  for (int q = 0; q < 16; ++q) {
    float4 a = ((const float4*)cb)[c0 * 16 + q];
    r0[4*q] = a.x; r0[4*q+1] = a.y; r0[4*q+2] = a.z; r0[4*q+3] = a.w;
    float4 bq = ((const float4*)cb)[c1 * 16 + q];
    r1[4*q] = bq.x; r1[4*q+1] = bq.y; r1[4*q+2] = bq.z; r1[4*q+3] = bq.w;
  }
  float ne0 = 0.f, ne1 = 0.f;
  #pragma unroll
  for (int d = 0; d < 64; ++d) { ne0 += r0[d] * r0[d]; ne1 += r1[d] * r1[d]; }
  const float rsne0 = 1.f / sqrtf(ne0), rsne1 = 1.f / sqrtf(ne1);
  const int wvid = tid >> 6;

  for (int it = 0; it < VQA_TOKS; ++it) {
    const int tok = blockIdx.x * VQA_TOKS + it;
    const float4* z4 = (const float4*)(ze + (size_t)tok * 64);
    float dot0 = 0.f, dot1 = 0.f;
    #pragma unroll
    for (int q = 0; q < 16; ++q) {
      float4 zv = z4[q];
      dot0 += zv.x * r0[4*q] + zv.y * r0[4*q+1] + zv.z * r0[4*q+2] + zv.w * r0[4*q+3];
      dot1 += zv.x * r1[4*q] + zv.y * r1[4*q+1] + zv.z * r1[4*q+2] + zv.w * r1[4*q+3];
    }
    const float nzv = nzbuf[tok];
    const float rsnz = 1.f / sqrtf(nzv);
    float dist0 = (-2.f * dot0 + nzv) + ne0;
    float dist1 = (-2.f * dot1 + nzv) + ne1;

    float* simrow = sim_out + (size_t)tok * 512;
    simrow[c0] = dot0 * rsnz * rsne0;
    simrow[c1] = dot1 * rsnz * rsne1;

    float md; int mi;
    if (dist1 < dist0) { md = dist1; mi = c1; } else { md = dist0; mi = c0; }
    #pragma unroll
    for (int off = 32; off; off >>= 1) {
      float od = __shfl_down(md, off);
      int   oi = __shfl_down(mi, off);
      if (od < md || (od == md && oi < mi)) { md = od; mi = oi; }
    }
    if ((tid & 63) == 0) pmin[tok * 4 + wvid] = make_float2(md, (float)mi);
  }
}

// ---------------- vq_finish: cross-wave argmin, z_q, ids, loss partial ----
__global__ __launch_bounds__(256) void vq_finish_kernel(
    const float* __restrict__ ze, const float* __restrict__ cb,
    const float2* __restrict__ pmin, float* __restrict__ zq,
    float* __restrict__ ids_out, float* __restrict__ blocksum)
{
  const int tid = threadIdx.x;
  const int lane = tid & 63, wvid = tid >> 6;
  float lloss = 0.f;
  for (int it = 0; it < 16; ++it) {
    const int tok = blockIdx.x * 64 + wvid * 16 + it;
    float2 p0 = pmin[tok * 4 + 0];
    float2 p1 = pmin[tok * 4 + 1];
    float2 p2 = pmin[tok * 4 + 2];
    float2 p3 = pmin[tok * 4 + 3];
    float bd = p0.x; int bi = (int)p0.y;
    { float d = p1.x; int i = (int)p1.y; if (d < bd || (d == bd && i < bi)) { bd = d; bi = i; } }
    { float d = p2.x; int i = (int)p2.y; if (d < bd || (d == bd && i < bi)) { bd = d; bi = i; } }
    { float d = p3.x; int i = (int)p3.y; if (d < bd || (d == bd && i < bi)) { bd = d; bi = i; } }
    float zev = ze[(size_t)tok * 64 + lane];
    float cv  = cb[(size_t)bi * 64 + lane];
    float df = zev - cv;
    float s = df * df;
    #pragma unroll
    for (int off = 32; off; off >>= 1) s += __shfl_down(s, off);
    zq[(size_t)tok * 64 + lane] = cv;
    if (lane == 0) { ids_out[tok] = (float)bi; lloss += sqrtf(s); }
  }
  __shared__ float ls[4];
  if (lane == 0) ls[wvid] = lloss;
  __syncthreads();
  if (tid == 0) blocksum[blockIdx.x] = ls[0] + ls[1] + ls[2] + ls[3];
}

__global__ void loss_fin_kernel(const float* __restrict__ blocksum,
                                float* __restrict__ out)
{
  const int lane = threadIdx.x;  // 64 threads
  float s = 0.f;
  for (int i = lane; i < 512; i += 64) s += blocksum[i];
  #pragma unroll
  for (int off = 32; off; off >>= 1) s += __shfl_down(s, off);
  if (lane == 0) out[0] = 1.25f * s / 32768.f;
}

// ---------------------------------------------------------------------------
extern "C" void kernel_launch(void* const* d_in, const int* in_sizes, int n_in,
                              void* d_out, int out_size, void* d_ws, size_t ws_size,
                              hipStream_t stream)
{
  const float* x       = (const float*)d_in[0];
  const float* w_down0 = (const float*)d_in[1];
  const float* b_down0 = (const float*)d_in[2];
  const float* w_down  = (const float*)d_in[3];
  const float* b_down  = (const float*)d_in[4];
  const float* w_res_e = (const float*)d_in[5];
  const float* b_res_e = (const float*)d_in[6];
  const float* cb      = (const float*)d_in[7];
  const float* w_res_d = (const float*)d_in[8];
  const float* b_res_d = (const float*)d_in[9];
  const float* w_up    = (const float*)d_in[10];
  const float* b_up    = (const float*)d_in[11];
  const float* w_proj  = (const float*)d_in[12];
  const float* b_proj  = (const float*)d_in[13];

  float* out = (float*)d_out;
  const size_t BUF = (size_t)4 * 65536 * 64;
  float*  bufA     = (float*)d_ws;
  float*  bufB     = bufA + BUF;
  float*  nzbuf    = bufB + BUF;
  float2* pmin     = (float2*)(nzbuf + 32768);
  float*  blocksum = (float*)(pmin + 32768 * 4);

  float* h = bufA;
  float* tmp = bufB;

  // ---- encoder ----
  down0_kernel<<<32768, 256, 0, stream>>>(x, w_down0, b_down0, h);
  int T = 32768;
  for (int blk = 0; blk < 3; ++blk) {
    if (blk > 0) {
      down2_kernel<<<dim3(T / 2 / 64, 4), 256, 0, stream>>>(
          h, w_down + (size_t)(blk - 1) * 4 * 64 * 64, b_down + (blk - 1) * 64, tmp, T);
      T >>= 1;
      float* s = h; h = tmp; tmp = s;
    }
    for (int r = 0; r < 4; ++r) {
      const float* w0p = w_res_e + (((size_t)blk * 4 + r) * 2 + 0) * 3 * 64 * 64;
      const float* w1p = w_res_e + (((size_t)blk * 4 + r) * 2 + 1) * 3 * 64 * 64;
      const float* b0p = b_res_e + (((size_t)blk * 4 + r) * 2 + 0) * 64;
      const float* b1p = b_res_e + (((size_t)blk * 4 + r) * 2 + 1) * 64;
      conv3_kernel<3, false><<<dim3(T / 128, 4), 256, 0, stream>>>(h, w0p, b0p, nullptr, tmp, T);
      conv3_kernel<1, true ><<<dim3(T / 128, 4), 256, 0, stream>>>(tmp, w1p, b1p, h, h, T);
    }
  }

  // ---- VQ (T == 8192, z_e in h; 32768 tokens) ----
  nz_kernel<<<8192, 256, 0, stream>>>(h, nzbuf);
  vq_dots_kernel<<<1024, 256, 0, stream>>>(h, cb, nzbuf, out + OFF_SIM, pmin);
  vq_finish_kernel<<<512, 256, 0, stream>>>(h, cb, pmin, tmp, out + OFF_IDS, blocksum);
  loss_fin_kernel<<<1, 64, 0, stream>>>(blocksum, out + OFF_LOSS);
  { float* s = h; h = tmp; tmp = s; }  // h = z_q

  // ---- decoder ----
  for (int blk = 0; blk < 3; ++blk) {
    for (int r = 0; r < 4; ++r) {
      const float* w0p = w_res_d + (((size_t)blk * 4 + r) * 2 + 0) * 3 * 64 * 64;
      const float* w1p = w_res_d + (((size_t)blk * 4 + r) * 2 + 1) * 3 * 64 * 64;
      const float* b0p = b_res_d + (((size_t)blk * 4 + r) * 2 + 0) * 64;
      const float* b1p = b_res_d + (((size_t)blk * 4 + r) * 2 + 1) * 64;
      conv3_kernel<1, false><<<dim3(T / 128, 4), 256, 0, stream>>>(h, w0p, b0p, nullptr, tmp, T);
      conv3_kernel<3, true ><<<dim3(T / 128, 4), 256, 0, stream>>>(tmp, w1p, b1p, h, h, T);
    }
    up_kernel<<<dim3(2 * T / 64, 4), 256, 0, stream>>>(
        h, w_up + (size_t)blk * 4 * 64 * 64, b_up + blk * 64, tmp, T);
    T <<= 1;
    float* s = h; h = tmp; tmp = s;
  }

  // ---- final projection (T == 65536) ----
  proj_kernel<<<1024, 256, 0, stream>>>(h, w_proj, b_proj, out);
}

// Round 3
// 2151.423 us; speedup vs baseline: 1.0843x; 1.0843x over previous
//
#include <hip/hip_runtime.h>
#include <cstdint>

// ---------------------------------------------------------------------------
// JukeboxAutoEncoder: fp32 implementation, round 3.
// Layout: all activations (B, T, C=64), C contiguous.
// Output layout (flat f32): x_hat[262144] | loss_vq[1] | ids[32768] | sim[16777216]
// Round-3 changes:
//  - conv3/down2/up: merged-k inner loop (x LDS values reused across all taps),
//    weights read as float4 directly from global (L2-backed) -- no weight LDS,
//    no per-k __syncthreads. xs-only LDS => 4 blocks/CU.
//  - conv3 templated on tile TT: 128 for T>=16384, 64 for T=8192 (grid size).
//  - vq_dots: z_e token tile staged in LDS once per block; inner loop is
//    LDS-broadcast reads + FMA (removes per-token global latency chain).
// ---------------------------------------------------------------------------

#define OFF_LOSS 262144
#define OFF_IDS  262145
#define OFF_SIM  294913

// ---------------- down0: (B,65536,1) -> (B,32768,64), K=4 stride2, relu ----
__global__ __launch_bounds__(256) void down0_kernel(
    const float* __restrict__ x, const float* __restrict__ w,
    const float* __restrict__ bias, float* __restrict__ y)
{
  int idx = blockIdx.x * 256 + threadIdx.x;   // enumerates (b, t, co)
  int co = idx & 63;
  int r  = idx >> 6;
  int t  = r & 32767;
  int b  = r >> 15;
  const float* xb = x + (size_t)b * 65536;
  float acc = bias[co];
  #pragma unroll
  for (int k = 0; k < 4; ++k) {
    int gt = 2 * t - 1 + k;
    float xv = ((unsigned)gt < 65536u) ? xb[gt] : 0.f;
    acc += xv * w[k * 64 + co];
  }
  y[(size_t)idx] = fmaxf(acc, 0.f);
}

// ---------------- conv3: K=3, dilation DIL, 64->64, relu, optional +res ----
// Merged-k inner loop; weights from global; TT outputs per block.
template <int DIL, bool HAS_RES, int TT>
__global__ __launch_bounds__(256, 4) void conv3_kernel(
    const float* __restrict__ x, const float* __restrict__ w,
    const float* __restrict__ bias, const float* res,
    float* y, int T)
{
  constexpr int TPT = TT / 16;               // outputs per thread in t
  constexpr int XT = TT + 2 * DIL;
  constexpr int XS = XT + 1;                 // odd stride -> conflict-free
  __shared__ float xs[64 * XS];
  const int tid = threadIdx.x;
  const int b   = blockIdx.y;
  const int t0  = blockIdx.x * TT;

  for (int e = tid; e < 64 * XT; e += 256) { // transpose to [ci][t]
    int tl = e >> 6, ci = e & 63;
    int gt = t0 - DIL + tl;
    float v = 0.f;
    if ((unsigned)gt < (unsigned)T) v = x[((size_t)b * T + gt) * 64 + ci];
    xs[ci * XS + tl] = v;
  }
  __syncthreads();

  const int co = (tid & 15) * 4;
  const int tb = (tid >> 4) * TPT;
  float acc[TPT][4] = {};
  const float4* wq = (const float4*)w;       // w[k][ci][co4]
  const int cq = co >> 2;

  #pragma unroll 2
  for (int ci = 0; ci < 64; ++ci) {
    float4 w0 = wq[(0 * 64 + ci) * 16 + cq];
    float4 w1 = wq[(1 * 64 + ci) * 16 + cq];
    float4 w2 = wq[(2 * 64 + ci) * 16 + cq];
    const float* xr = xs + ci * XS + tb;
    float xv[TPT + 2 * DIL];
    #pragma unroll
    for (int i = 0; i < TPT + 2 * DIL; ++i) xv[i] = xr[i];
    #pragma unroll
    for (int i = 0; i < TPT; ++i) {
      float a0 = xv[i], a1 = xv[i + DIL], a2 = xv[i + 2 * DIL];
      acc[i][0] = fmaf(a0, w0.x, fmaf(a1, w1.x, fmaf(a2, w2.x, acc[i][0])));
      acc[i][1] = fmaf(a0, w0.y, fmaf(a1, w1.y, fmaf(a2, w2.y, acc[i][1])));
      acc[i][2] = fmaf(a0, w0.z, fmaf(a1, w1.z, fmaf(a2, w2.z, acc[i][2])));
      acc[i][3] = fmaf(a0, w0.w, fmaf(a1, w1.w, fmaf(a2, w2.w, acc[i][3])));
    }
  }

  float4 bv = *(const float4*)&bias[co];
  #pragma unroll
  for (int i = 0; i < TPT; ++i) {
    size_t o = ((size_t)b * T + t0 + tb + i) * 64 + co;
    float4 rr;
    rr.x = fmaxf(acc[i][0] + bv.x, 0.f);
    rr.y = fmaxf(acc[i][1] + bv.y, 0.f);
    rr.z = fmaxf(acc[i][2] + bv.z, 0.f);
    rr.w = fmaxf(acc[i][3] + bv.w, 0.f);
    if (HAS_RES) {
      float4 rv = *(const float4*)&res[o];
      rr.x += rv.x; rr.y += rv.y; rr.z += rv.z; rr.w += rv.w;
    }
    *(float4*)&y[o] = rr;
  }
}

// ---------------- down2: K=4 stride2, 64->64, relu (merged-k) -------------
__global__ __launch_bounds__(256, 4) void down2_kernel(
    const float* __restrict__ x, const float* __restrict__ w,
    const float* __restrict__ bias, float* __restrict__ y, int Tin)
{
  constexpr int XT = 130, XS = 131;
  __shared__ float xs[64 * XS];
  const int tid = threadIdx.x;
  const int b   = blockIdx.y;
  const int t0  = blockIdx.x * 64;
  const int Tout = Tin >> 1;

  for (int e = tid; e < 64 * XT; e += 256) {
    int tl = e >> 6, ci = e & 63;
    int gt = 2 * t0 - 1 + tl;
    float v = 0.f;
    if ((unsigned)gt < (unsigned)Tin) v = x[((size_t)b * Tin + gt) * 64 + ci];
    xs[ci * XS + tl] = v;
  }
  __syncthreads();

  const int co = (tid & 15) * 4;
  const int tb = (tid >> 4) * 4;
  float acc[4][4] = {};
  const float4* wq = (const float4*)w;
  const int cq = co >> 2;

  #pragma unroll 2
  for (int ci = 0; ci < 64; ++ci) {
    float4 w0 = wq[(0 * 64 + ci) * 16 + cq];
    float4 w1 = wq[(1 * 64 + ci) * 16 + cq];
    float4 w2 = wq[(2 * 64 + ci) * 16 + cq];
    float4 w3 = wq[(3 * 64 + ci) * 16 + cq];
    const float* xr = xs + ci * XS + 2 * tb;
    float xv[10];
    #pragma unroll
    for (int i = 0; i < 10; ++i) xv[i] = xr[i];
    #pragma unroll
    for (int i = 0; i < 4; ++i) {
      float a0 = xv[2*i], a1 = xv[2*i+1], a2 = xv[2*i+2], a3 = xv[2*i+3];
      acc[i][0] = fmaf(a0, w0.x, fmaf(a1, w1.x, fmaf(a2, w2.x, fmaf(a3, w3.x, acc[i][0]))));
      acc[i][1] = fmaf(a0, w0.y, fmaf(a1, w1.y, fmaf(a2, w2.y, fmaf(a3, w3.y, acc[i][1]))));
      acc[i][2] = fmaf(a0, w0.z, fmaf(a1, w1.z, fmaf(a2, w2.z, fmaf(a3, w3.z, acc[i][2]))));
      acc[i][3] = fmaf(a0, w0.w, fmaf(a1, w1.w, fmaf(a2, w2.w, fmaf(a3, w3.w, acc[i][3]))));
    }
  }

  float4 bv = *(const float4*)&bias[co];
  #pragma unroll
  for (int i = 0; i < 4; ++i) {
    size_t o = ((size_t)b * Tout + t0 + tb + i) * 64 + co;
    float4 rr;
    rr.x = fmaxf(acc[i][0] + bv.x, 0.f);
    rr.y = fmaxf(acc[i][1] + bv.y, 0.f);
    rr.z = fmaxf(acc[i][2] + bv.z, 0.f);
    rr.w = fmaxf(acc[i][3] + bv.w, 0.f);
    *(float4*)&y[o] = rr;
  }
}

// ---------------- up: conv_transpose K=4 stride2, 64->64, relu (merged-k) -
// y[2u]   = relu(b + w0^T x[u-1] + w2^T x[u])
// y[2u+1] = relu(b + w1^T x[u]   + w3^T x[u+1])
__global__ __launch_bounds__(256, 4) void up_kernel(
    const float* __restrict__ x, const float* __restrict__ w,
    const float* __restrict__ bias, float* __restrict__ y, int Tin)
{
  constexpr int XT = 34, XS = 35;
  __shared__ float xs[64 * XS];
  const int tid = threadIdx.x;
  const int b   = blockIdx.y;
  const int t0  = blockIdx.x * 64;
  const int u0  = t0 >> 1;
  const int Tout = Tin << 1;

  for (int e = tid; e < 64 * XT; e += 256) {
    int ul = e >> 6, ci = e & 63;
    int gu = u0 - 1 + ul;
    float v = 0.f;
    if ((unsigned)gu < (unsigned)Tin) v = x[((size_t)b * Tin + gu) * 64 + ci];
    xs[ci * XS + ul] = v;
  }
  __syncthreads();

  const int co = (tid & 15) * 4;
  const int tb = (tid >> 4) * 4;
  const int ub = tb >> 1;
  float acc[4][4] = {};
  const float4* wq = (const float4*)w;
  const int cq = co >> 2;

  #pragma unroll 2
  for (int ci = 0; ci < 64; ++ci) {
    float4 w0 = wq[(0 * 64 + ci) * 16 + cq];
    float4 w1 = wq[(1 * 64 + ci) * 16 + cq];
    float4 w2 = wq[(2 * 64 + ci) * 16 + cq];
    float4 w3 = wq[(3 * 64 + ci) * 16 + cq];
    const float* xr = xs + ci * XS + ub;
    float xv0 = xr[0], xv1 = xr[1], xv2 = xr[2], xv3 = xr[3];
    // acc[0]=even(u=ub): w0*x[u-1]+w2*x[u]; acc[1]=odd: w1*x[u]+w3*x[u+1]
    // acc[2]=even(u=ub+1), acc[3]=odd(u=ub+1)
    acc[0][0] = fmaf(xv0, w0.x, fmaf(xv1, w2.x, acc[0][0]));
    acc[0][1] = fmaf(xv0, w0.y, fmaf(xv1, w2.y, acc[0][1]));
    acc[0][2] = fmaf(xv0, w0.z, fmaf(xv1, w2.z, acc[0][2]));
    acc[0][3] = fmaf(xv0, w0.w, fmaf(xv1, w2.w, acc[0][3]));
    acc[1][0] = fmaf(xv1, w1.x, fmaf(xv2, w3.x, acc[1][0]));
    acc[1][1] = fmaf(xv1, w1.y, fmaf(xv2, w3.y, acc[1][1]));
    acc[1][2] = fmaf(xv1, w1.z, fmaf(xv2, w3.z, acc[1][2]));
    acc[1][3] = fmaf(xv1, w1.w, fmaf(xv2, w3.w, acc[1][3]));
    acc[2][0] = fmaf(xv1, w0.x, fmaf(xv2, w2.x, acc[2][0]));
    acc[2][1] = fmaf(xv1, w0.y, fmaf(xv2, w2.y, acc[2][1]));
    acc[2][2] = fmaf(xv1, w0.z, fmaf(xv2, w2.z, acc[2][2]));
    acc[2][3] = fmaf(xv1, w0.w, fmaf(xv2, w2.w, acc[2][3]));
    acc[3][0] = fmaf(xv2, w1.x, fmaf(xv3, w3.x, acc[3][0]));
    acc[3][1] = fmaf(xv2, w1.y, fmaf(xv3, w3.y, acc[3][1]));
    acc[3][2] = fmaf(xv2, w1.z, fmaf(xv3, w3.z, acc[3][2]));
    acc[3][3] = fmaf(xv2, w1.w, fmaf(xv3, w3.w, acc[3][3]));
  }

  float4 bv = *(const float4*)&bias[co];
  #pragma unroll
  for (int i = 0; i < 4; ++i) {
    size_t o = ((size_t)b * Tout + t0 + tb + i) * 64 + co;
    float4 rr;
    rr.x = fmaxf(acc[i][0] + bv.x, 0.f);
    rr.y = fmaxf(acc[i][1] + bv.y, 0.f);
    rr.z = fmaxf(acc[i][2] + bv.z, 0.f);
    rr.w = fmaxf(acc[i][3] + bv.w, 0.f);
    *(float4*)&y[o] = rr;
  }
}

// ---------------- proj: K=3 dil1, 64->1, linear ---------------------------
__global__ __launch_bounds__(256) void proj_kernel(
    const float* __restrict__ x, const float* __restrict__ w,
    const float* __restrict__ bias, float* __restrict__ out)
{
  const int lane = threadIdx.x & 63;
  const int wid  = (blockIdx.x * 256 + threadIdx.x) >> 6;  // 4096 waves
  const float w0 = w[lane], w1 = w[64 + lane], w2 = w[128 + lane];
  const float bb = bias[0];
  size_t base = (size_t)wid * 64;
  for (int i = 0; i < 64; ++i) {
    size_t tau = base + i;
    int b = (int)(tau >> 16);
    int t = (int)(tau & 65535);
    const float* xb = x + ((size_t)b * 65536) * 64;
    float pm = (t > 0)     ? xb[(size_t)(t - 1) * 64 + lane] : 0.f;
    float pc =               xb[(size_t)t * 64 + lane];
    float pp = (t < 65535) ? xb[(size_t)(t + 1) * 64 + lane] : 0.f;
    float s = pm * w0 + pc * w1 + pp * w2;
    #pragma unroll
    for (int off = 32; off; off >>= 1) s += __shfl_down(s, off);
    if (lane == 0) out[tau] = s + bb;
  }
}

// ---------------- nz: per-token sum of squares ----------------------------
__global__ __launch_bounds__(256) void nz_kernel(
    const float* __restrict__ ze, float* __restrict__ nz)
{
  int lane = threadIdx.x & 63;
  int tok  = (blockIdx.x * 256 + threadIdx.x) >> 6;  // 32768 waves
  float v = ze[(size_t)tok * 64 + lane];
  float s = v * v;
  #pragma unroll
  for (int off = 32; off; off >>= 1) s += __shfl_down(s, off);
  if (lane == 0) nz[tok] = s;
}

// ---------------- vq_dots: dists + sim + per-wave argmin ------------------
// z_e token tile staged in LDS; codebook (2 rows/thread) in registers.
#define VQA_TOKS 32
__global__ __launch_bounds__(256) void vq_dots_kernel(
    const float* __restrict__ ze, const float* __restrict__ cb,
    const float* __restrict__ nzbuf, float* __restrict__ sim_out,
    float2* __restrict__ pmin)
{
  __shared__ float zs[VQA_TOKS * 64];        // 8 KB
  const int tid = threadIdx.x;
  {
    const float4* src = (const float4*)(ze + (size_t)blockIdx.x * VQA_TOKS * 64);
    float4* dst = (float4*)zs;
    #pragma unroll
    for (int i = 0; i < VQA_TOKS * 16 / 256; ++i) dst[tid + i * 256] = src[tid + i * 256];
  }

  const int c0 = tid, c1 = tid + 256;
  float r0[64], r1[64];
  #pragma unroll
  for (int q = 0; q < 16; ++q) {
    float4 a = ((const float4*)cb)[c0 * 16 + q];
    r0[4*q] = a.x; r0[4*q+1] = a.y; r0[4*q+2] = a.z; r0[4*q+3] = a.w;
    float4 bq = ((const float4*)cb)[c1 * 16 + q];
    r1[4*q] = bq.x; r1[4*q+1] = bq.y; r1[4*q+2] = bq.z; r1[4*q+3] = bq.w;
  }
  float ne0 = 0.f, ne1 = 0.f;
  #pragma unroll
  for (int d = 0; d < 64; ++d) { ne0 += r0[d] * r0[d]; ne1 += r1[d] * r1[d]; }
  const float rsne0 = 1.f / sqrtf(ne0), rsne1 = 1.f / sqrtf(ne1);
  const int wvid = tid >> 6;
  __syncthreads();

  for (int it = 0; it < VQA_TOKS; ++it) {
    const int tok = blockIdx.x * VQA_TOKS + it;
    const float4* z4 = (const float4*)(zs + it * 64);   // LDS broadcast reads
    float dot0 = 0.f, dot1 = 0.f;
    #pragma unroll
    for (int q = 0; q < 16; ++q) {
      float4 zv = z4[q];
      dot0 += zv.x * r0[4*q] + zv.y * r0[4*q+1] + zv.z * r0[4*q+2] + zv.w * r0[4*q+3];
      dot1 += zv.x * r1[4*q] + zv.y * r1[4*q+1] + zv.z * r1[4*q+2] + zv.w * r1[4*q+3];
    }
    const float nzv = nzbuf[tok];
    const float rsnz = 1.f / sqrtf(nzv);
    float dist0 = (-2.f * dot0 + nzv) + ne0;
    float dist1 = (-2.f * dot1 + nzv) + ne1;

    float* simrow = sim_out + (size_t)tok * 512;
    simrow[c0] = dot0 * rsnz * rsne0;
    simrow[c1] = dot1 * rsnz * rsne1;

    float md; int mi;
    if (dist1 < dist0) { md = dist1; mi = c1; } else { md = dist0; mi = c0; }
    #pragma unroll
    for (int off = 32; off; off >>= 1) {
      float od = __shfl_down(md, off);
      int   oi = __shfl_down(mi, off);
      if (od < md || (od == md && oi < mi)) { md = od; mi = oi; }
    }
    if ((tid & 63) == 0) pmin[tok * 4 + wvid] = make_float2(md, (float)mi);
  }
}

// ---------------- vq_finish: cross-wave argmin, z_q, ids, loss partial ----
__global__ __launch_bounds__(256) void vq_finish_kernel(
    const float* __restrict__ ze, const float* __restrict__ cb,
    const float2* __restrict__ pmin, float* __restrict__ zq,
    float* __restrict__ ids_out, float* __restrict__ blocksum)
{
  const int tid = threadIdx.x;
  const int lane = tid & 63, wvid = tid >> 6;
  float lloss = 0.f;
  for (int it = 0; it < 16; ++it) {
    const int tok = blockIdx.x * 64 + wvid * 16 + it;
    float2 p0 = pmin[tok * 4 + 0];
    float2 p1 = pmin[tok * 4 + 1];
    float2 p2 = pmin[tok * 4 + 2];
    float2 p3 = pmin[tok * 4 + 3];
    float bd = p0.x; int bi = (int)p0.y;
    { float d = p1.x; int i = (int)p1.y; if (d < bd || (d == bd && i < bi)) { bd = d; bi = i; } }
    { float d = p2.x; int i = (int)p2.y; if (d < bd || (d == bd && i < bi)) { bd = d; bi = i; } }
    { float d = p3.x; int i = (int)p3.y; if (d < bd || (d == bd && i < bi)) { bd = d; bi = i; } }
    float zev = ze[(size_t)tok * 64 + lane];
    float cv  = cb[(size_t)bi * 64 + lane];
    float df = zev - cv;
    float s = df * df;
    #pragma unroll
    for (int off = 32; off; off >>= 1) s += __shfl_down(s, off);
    zq[(size_t)tok * 64 + lane] = cv;
    if (lane == 0) { ids_out[tok] = (float)bi; lloss += sqrtf(s); }
  }
  __shared__ float ls[4];
  if (lane == 0) ls[wvid] = lloss;
  __syncthreads();
  if (tid == 0) blocksum[blockIdx.x] = ls[0] + ls[1] + ls[2] + ls[3];
}

__global__ void loss_fin_kernel(const float* __restrict__ blocksum,
                                float* __restrict__ out)
{
  const int lane = threadIdx.x;  // 64 threads
  float s = 0.f;
  for (int i = lane; i < 512; i += 64) s += blocksum[i];
  #pragma unroll
  for (int off = 32; off; off >>= 1) s += __shfl_down(s, off);
  if (lane == 0) out[0] = 1.25f * s / 32768.f;
}

// ---------------------------------------------------------------------------
#define LAUNCH_CONV3(DILV, RESV, XP, WP, BP, RP, YP)                           \
  do {                                                                         \
    if (T >= 16384)                                                            \
      conv3_kernel<DILV, RESV, 128><<<dim3(T / 128, 4), 256, 0, stream>>>(     \
          XP, WP, BP, RP, YP, T);                                              \
    else                                                                       \
      conv3_kernel<DILV, RESV, 64><<<dim3(T / 64, 4), 256, 0, stream>>>(       \
          XP, WP, BP, RP, YP, T);                                              \
  } while (0)

extern "C" void kernel_launch(void* const* d_in, const int* in_sizes, int n_in,
                              void* d_out, int out_size, void* d_ws, size_t ws_size,
                              hipStream_t stream)
{
  const float* x       = (const float*)d_in[0];
  const float* w_down0 = (const float*)d_in[1];
  const float* b_down0 = (const float*)d_in[2];
  const float* w_down  = (const float*)d_in[3];
  const float* b_down  = (const float*)d_in[4];
  const float* w_res_e = (const float*)d_in[5];
  const float* b_res_e = (const float*)d_in[6];
  const float* cb      = (const float*)d_in[7];
  const float* w_res_d = (const float*)d_in[8];
  const float* b_res_d = (const float*)d_in[9];
  const float* w_up    = (const float*)d_in[10];
  const float* b_up    = (const float*)d_in[11];
  const float* w_proj  = (const float*)d_in[12];
  const float* b_proj  = (const float*)d_in[13];

  float* out = (float*)d_out;
  const size_t BUF = (size_t)4 * 65536 * 64;
  float*  bufA     = (float*)d_ws;
  float*  bufB     = bufA + BUF;
  float*  nzbuf    = bufB + BUF;
  float2* pmin     = (float2*)(nzbuf + 32768);
  float*  blocksum = (float*)(pmin + 32768 * 4);

  float* h = bufA;
  float* tmp = bufB;

  // ---- encoder ----
  down0_kernel<<<32768, 256, 0, stream>>>(x, w_down0, b_down0, h);
  int T = 32768;
  for (int blk = 0; blk < 3; ++blk) {
    if (blk > 0) {
      down2_kernel<<<dim3(T / 2 / 64, 4), 256, 0, stream>>>(
          h, w_down + (size_t)(blk - 1) * 4 * 64 * 64, b_down + (blk - 1) * 64, tmp, T);
      T >>= 1;
      float* s = h; h = tmp; tmp = s;
    }
    for (int r = 0; r < 4; ++r) {
      const float* w0p = w_res_e + (((size_t)blk * 4 + r) * 2 + 0) * 3 * 64 * 64;
      const float* w1p = w_res_e + (((size_t)blk * 4 + r) * 2 + 1) * 3 * 64 * 64;
      const float* b0p = b_res_e + (((size_t)blk * 4 + r) * 2 + 0) * 64;
      const float* b1p = b_res_e + (((size_t)blk * 4 + r) * 2 + 1) * 64;
      LAUNCH_CONV3(3, false, h, w0p, b0p, nullptr, tmp);
      LAUNCH_CONV3(1, true,  tmp, w1p, b1p, h, h);
    }
  }

  // ---- VQ (T == 8192, z_e in h; 32768 tokens) ----
  nz_kernel<<<8192, 256, 0, stream>>>(h, nzbuf);
  vq_dots_kernel<<<1024, 256, 0, stream>>>(h, cb, nzbuf, out + OFF_SIM, pmin);
  vq_finish_kernel<<<512, 256, 0, stream>>>(h, cb, pmin, tmp, out + OFF_IDS, blocksum);
  loss_fin_kernel<<<1, 64, 0, stream>>>(blocksum, out + OFF_LOSS);
  { float* s = h; h = tmp; tmp = s; }  // h = z_q

  // ---- decoder ----
  for (int blk = 0; blk < 3; ++blk) {
    for (int r = 0; r < 4; ++r) {
      const float* w0p = w_res_d + (((size_t)blk * 4 + r) * 2 + 0) * 3 * 64 * 64;
      const float* w1p = w_res_d + (((size_t)blk * 4 + r) * 2 + 1) * 3 * 64 * 64;
      const float* b0p = b_res_d + (((size_t)blk * 4 + r) * 2 + 0) * 64;
      const float* b1p = b_res_d + (((size_t)blk * 4 + r) * 2 + 1) * 64;
      LAUNCH_CONV3(1, false, h, w0p, b0p, nullptr, tmp);
      LAUNCH_CONV3(3, true,  tmp, w1p, b1p, h, h);
    }
    up_kernel<<<dim3(2 * T / 64, 4), 256, 0, stream>>>(
        h, w_up + (size_t)blk * 4 * 64 * 64, b_up + blk * 64, tmp, T);
    T <<= 1;
    float* s = h; h = tmp; tmp = s;
  }

  // ---- final projection (T == 65536) ----
  proj_kernel<<<1024, 256, 0, stream>>>(h, w_proj, b_proj, out);
}

// Round 4
// 1981.076 us; speedup vs baseline: 1.1776x; 1.0860x over previous
//
#include <hip/hip_runtime.h>
#include <cstdint>

// ---------------------------------------------------------------------------
// JukeboxAutoEncoder fp32, round 4.
// Key structure: "scalar-weight" convs — lane = time position, each wave owns
// a wave-uniform 8-channel output group (co0 via readfirstlane), so weights
// are s_load (SMEM broadcast) and x comes from stride-1 LDS reads.
// Output layout (flat f32): x_hat[262144] | loss_vq[1] | ids[32768] | sim[16777216]
// ---------------------------------------------------------------------------

#define OFF_LOSS 262144
#define OFF_IDS  262145
#define OFF_SIM  294913

// ---------------- down0: (B,65536,1) -> (B,32768,64), K=4 stride2, relu ----
__global__ __launch_bounds__(256) void down0_kernel(
    const float* __restrict__ x, const float* __restrict__ w,
    const float* __restrict__ bias, float* __restrict__ y)
{
  int idx = blockIdx.x * 256 + threadIdx.x;   // enumerates (b, t, co)
  int co = idx & 63;
  int r  = idx >> 6;
  int t  = r & 32767;
  int b  = r >> 15;
  const float* xb = x + (size_t)b * 65536;
  float acc = bias[co];
  #pragma unroll
  for (int k = 0; k < 4; ++k) {
    int gt = 2 * t - 1 + k;
    float xv = ((unsigned)gt < 65536u) ? xb[gt] : 0.f;
    acc += xv * w[k * 64 + co];
  }
  y[(size_t)idx] = fmaxf(acc, 0.f);
}

// ---------------- conv3: K=3, dil DIL, 64->64, relu, optional +res --------
// Block: 256 thr = 4 waves; wave handles co0..co0+7 (co0 wave-uniform),
// lane = t; 2 t per lane (t0+lane, t0+lane+64). grid (T/128, 2, 4).
template <int DIL, bool HAS_RES>
__global__ __launch_bounds__(256, 4) void conv3_kernel(
    const float* __restrict__ x, const float* __restrict__ w,
    const float* __restrict__ bias, const float* res,
    float* y, int T)
{
  constexpr int TT = 128;
  constexpr int XT = TT + 2 * DIL;
  constexpr int XS = XT + 1;                 // odd stride
  __shared__ float xs[64 * XS];
  const int tid  = threadIdx.x;
  const int lane = tid & 63;
  const int b    = blockIdx.z;
  const int t0   = blockIdx.x * TT;
  const int wv   = __builtin_amdgcn_readfirstlane(tid >> 6);
  const int co0  = __builtin_amdgcn_readfirstlane(blockIdx.y * 32 + wv * 8);

  const float* xb = x + (size_t)b * T * 64;
  for (int e = tid; e < 16 * XT; e += 256) { // transpose to [ci][t]
    int tl = e >> 4, cq = (e & 15) * 4;
    int gt = t0 - DIL + tl;
    float4 v = make_float4(0.f, 0.f, 0.f, 0.f);
    if ((unsigned)gt < (unsigned)T) v = *(const float4*)&xb[(size_t)gt * 64 + cq];
    xs[(cq + 0) * XS + tl] = v.x;
    xs[(cq + 1) * XS + tl] = v.y;
    xs[(cq + 2) * XS + tl] = v.z;
    xs[(cq + 3) * XS + tl] = v.w;
  }
  __syncthreads();

  float acc0[8] = {}, acc1[8] = {};
  const float* wb = w + co0;                 // w[k][ci][co0..co0+7]
  #pragma unroll 2
  for (int ci = 0; ci < 64; ++ci) {
    const float* xr = xs + ci * XS + lane;
    float a0 = xr[0],  a1 = xr[DIL],      a2 = xr[2 * DIL];
    float b0 = xr[64], b1 = xr[64 + DIL], b2 = xr[64 + 2 * DIL];
    const float* w0 = wb + (0 * 64 + ci) * 64;
    const float* w1 = wb + (1 * 64 + ci) * 64;
    const float* w2 = wb + (2 * 64 + ci) * 64;
    #pragma unroll
    for (int j = 0; j < 8; ++j) {
      float c0 = w0[j], c1 = w1[j], c2 = w2[j];
      acc0[j] = fmaf(a0, c0, fmaf(a1, c1, fmaf(a2, c2, acc0[j])));
      acc1[j] = fmaf(b0, c0, fmaf(b1, c1, fmaf(b2, c2, acc1[j])));
    }
  }

  float bs[8];
  #pragma unroll
  for (int j = 0; j < 8; ++j) bs[j] = bias[co0 + j];
  size_t o0 = ((size_t)b * T + t0 + lane) * 64 + co0;
  size_t o1 = o0 + (size_t)64 * 64;
  float4 r0a, r0b, r1a, r1b;
  r0a.x = fmaxf(acc0[0] + bs[0], 0.f); r0a.y = fmaxf(acc0[1] + bs[1], 0.f);
  r0a.z = fmaxf(acc0[2] + bs[2], 0.f); r0a.w = fmaxf(acc0[3] + bs[3], 0.f);
  r0b.x = fmaxf(acc0[4] + bs[4], 0.f); r0b.y = fmaxf(acc0[5] + bs[5], 0.f);
  r0b.z = fmaxf(acc0[6] + bs[6], 0.f); r0b.w = fmaxf(acc0[7] + bs[7], 0.f);
  r1a.x = fmaxf(acc1[0] + bs[0], 0.f); r1a.y = fmaxf(acc1[1] + bs[1], 0.f);
  r1a.z = fmaxf(acc1[2] + bs[2], 0.f); r1a.w = fmaxf(acc1[3] + bs[3], 0.f);
  r1b.x = fmaxf(acc1[4] + bs[4], 0.f); r1b.y = fmaxf(acc1[5] + bs[5], 0.f);
  r1b.z = fmaxf(acc1[6] + bs[6], 0.f); r1b.w = fmaxf(acc1[7] + bs[7], 0.f);
  if (HAS_RES) {
    float4 v0a = *(const float4*)&res[o0];
    float4 v0b = *(const float4*)&res[o0 + 4];
    float4 v1a = *(const float4*)&res[o1];
    float4 v1b = *(const float4*)&res[o1 + 4];
    r0a.x += v0a.x; r0a.y += v0a.y; r0a.z += v0a.z; r0a.w += v0a.w;
    r0b.x += v0b.x; r0b.y += v0b.y; r0b.z += v0b.z; r0b.w += v0b.w;
    r1a.x += v1a.x; r1a.y += v1a.y; r1a.z += v1a.z; r1a.w += v1a.w;
    r1b.x += v1b.x; r1b.y += v1b.y; r1b.z += v1b.z; r1b.w += v1b.w;
  }
  *(float4*)&y[o0]     = r0a;
  *(float4*)&y[o0 + 4] = r0b;
  *(float4*)&y[o1]     = r1a;
  *(float4*)&y[o1 + 4] = r1b;
}

// ---------------- down2: K=4 stride2, 64->64, relu ------------------------
// Block: 64 outputs in t; lane = out t; 8 co per wave. grid (Tout/64, 2, 4).
__global__ __launch_bounds__(256, 4) void down2_kernel(
    const float* __restrict__ x, const float* __restrict__ w,
    const float* __restrict__ bias, float* __restrict__ y, int Tin)
{
  constexpr int XT = 130, XS = 131;
  __shared__ float xs[64 * XS];
  const int tid  = threadIdx.x;
  const int lane = tid & 63;
  const int b    = blockIdx.z;
  const int t0   = blockIdx.x * 64;
  const int Tout = Tin >> 1;
  const int wv   = __builtin_amdgcn_readfirstlane(tid >> 6);
  const int co0  = __builtin_amdgcn_readfirstlane(blockIdx.y * 32 + wv * 8);

  const float* xb = x + (size_t)b * Tin * 64;
  for (int e = tid; e < 16 * XT; e += 256) {
    int tl = e >> 4, cq = (e & 15) * 4;
    int gt = 2 * t0 - 1 + tl;
    float4 v = make_float4(0.f, 0.f, 0.f, 0.f);
    if ((unsigned)gt < (unsigned)Tin) v = *(const float4*)&xb[(size_t)gt * 64 + cq];
    xs[(cq + 0) * XS + tl] = v.x;
    xs[(cq + 1) * XS + tl] = v.y;
    xs[(cq + 2) * XS + tl] = v.z;
    xs[(cq + 3) * XS + tl] = v.w;
  }
  __syncthreads();

  float acc[8] = {};
  const float* wb = w + co0;
  #pragma unroll 2
  for (int ci = 0; ci < 64; ++ci) {
    const float* xr = xs + ci * XS + 2 * lane;
    float a0 = xr[0], a1 = xr[1], a2 = xr[2], a3 = xr[3];
    const float* w0 = wb + (0 * 64 + ci) * 64;
    const float* w1 = wb + (1 * 64 + ci) * 64;
    const float* w2 = wb + (2 * 64 + ci) * 64;
    const float* w3 = wb + (3 * 64 + ci) * 64;
    #pragma unroll
    for (int j = 0; j < 8; ++j)
      acc[j] = fmaf(a0, w0[j], fmaf(a1, w1[j], fmaf(a2, w2[j], fmaf(a3, w3[j], acc[j]))));
  }

  size_t o = ((size_t)b * Tout + t0 + lane) * 64 + co0;
  float4 ra, rb;
  ra.x = fmaxf(acc[0] + bias[co0 + 0], 0.f); ra.y = fmaxf(acc[1] + bias[co0 + 1], 0.f);
  ra.z = fmaxf(acc[2] + bias[co0 + 2], 0.f); ra.w = fmaxf(acc[3] + bias[co0 + 3], 0.f);
  rb.x = fmaxf(acc[4] + bias[co0 + 4], 0.f); rb.y = fmaxf(acc[5] + bias[co0 + 5], 0.f);
  rb.z = fmaxf(acc[6] + bias[co0 + 6], 0.f); rb.w = fmaxf(acc[7] + bias[co0 + 7], 0.f);
  *(float4*)&y[o]     = ra;
  *(float4*)&y[o + 4] = rb;
}

// ---------------- up: conv_transpose K=4 stride2, 64->64, relu ------------
// y[2u] = relu(b + w0^T x[u-1] + w2^T x[u]); y[2u+1] = relu(b + w1^T x[u] + w3^T x[u+1])
// Block: 128 outputs (64 u); lane handles t-pair (2lane, 2lane+1); 8 co/wave.
// grid (Tout/128, 2, 4).
__global__ __launch_bounds__(256, 4) void up_kernel(
    const float* __restrict__ x, const float* __restrict__ w,
    const float* __restrict__ bias, float* __restrict__ y, int Tin)
{
  constexpr int XT = 66, XS = 67;
  __shared__ float xs[64 * XS];
  const int tid  = threadIdx.x;
  const int lane = tid & 63;
  const int b    = blockIdx.z;
  const int u0   = blockIdx.x * 64;
  const int Tout = Tin << 1;
  const int wv   = __builtin_amdgcn_readfirstlane(tid >> 6);
  const int co0  = __builtin_amdgcn_readfirstlane(blockIdx.y * 32 + wv * 8);

  const float* xb = x + (size_t)b * Tin * 64;
  for (int e = tid; e < 16 * XT; e += 256) {
    int ul = e >> 4, cq = (e & 15) * 4;
    int gu = u0 - 1 + ul;
    float4 v = make_float4(0.f, 0.f, 0.f, 0.f);
    if ((unsigned)gu < (unsigned)Tin) v = *(const float4*)&xb[(size_t)gu * 64 + cq];
    xs[(cq + 0) * XS + ul] = v.x;
    xs[(cq + 1) * XS + ul] = v.y;
    xs[(cq + 2) * XS + ul] = v.z;
    xs[(cq + 3) * XS + ul] = v.w;
  }
  __syncthreads();

  float acce[8] = {}, acco[8] = {};
  const float* wb = w + co0;
  #pragma unroll 2
  for (int ci = 0; ci < 64; ++ci) {
    const float* xr = xs + ci * XS + lane;
    float a0 = xr[0], a1 = xr[1], a2 = xr[2];  // x[u-1], x[u], x[u+1]
    const float* w0 = wb + (0 * 64 + ci) * 64;
    const float* w1 = wb + (1 * 64 + ci) * 64;
    const float* w2 = wb + (2 * 64 + ci) * 64;
    const float* w3 = wb + (3 * 64 + ci) * 64;
    #pragma unroll
    for (int j = 0; j < 8; ++j) {
      acce[j] = fmaf(a0, w0[j], fmaf(a1, w2[j], acce[j]));
      acco[j] = fmaf(a1, w1[j], fmaf(a2, w3[j], acco[j]));
    }
  }

  float bs[8];
  #pragma unroll
  for (int j = 0; j < 8; ++j) bs[j] = bias[co0 + j];
  size_t oe = ((size_t)b * Tout + 2 * (u0 + lane)) * 64 + co0;
  size_t oo = oe + 64;
  float4 ea, eb, oa, ob;
  ea.x = fmaxf(acce[0] + bs[0], 0.f); ea.y = fmaxf(acce[1] + bs[1], 0.f);
  ea.z = fmaxf(acce[2] + bs[2], 0.f); ea.w = fmaxf(acce[3] + bs[3], 0.f);
  eb.x = fmaxf(acce[4] + bs[4], 0.f); eb.y = fmaxf(acce[5] + bs[5], 0.f);
  eb.z = fmaxf(acce[6] + bs[6], 0.f); eb.w = fmaxf(acce[7] + bs[7], 0.f);
  oa.x = fmaxf(acco[0] + bs[0], 0.f); oa.y = fmaxf(acco[1] + bs[1], 0.f);
  oa.z = fmaxf(acco[2] + bs[2], 0.f); oa.w = fmaxf(acco[3] + bs[3], 0.f);
  ob.x = fmaxf(acco[4] + bs[4], 0.f); ob.y = fmaxf(acco[5] + bs[5], 0.f);
  ob.z = fmaxf(acco[6] + bs[6], 0.f); ob.w = fmaxf(acco[7] + bs[7], 0.f);
  *(float4*)&y[oe]     = ea;
  *(float4*)&y[oe + 4] = eb;
  *(float4*)&y[oo]     = oa;
  *(float4*)&y[oo + 4] = ob;
}

// ---------------- proj: K=3 dil1, 64->1, linear ---------------------------
__global__ __launch_bounds__(256) void proj_kernel(
    const float* __restrict__ x, const float* __restrict__ w,
    const float* __restrict__ bias, float* __restrict__ out)
{
  const int lane = threadIdx.x & 63;
  const int wid  = (blockIdx.x * 256 + threadIdx.x) >> 6;  // 4096 waves
  const float w0 = w[lane], w1 = w[64 + lane], w2 = w[128 + lane];
  const float bb = bias[0];
  size_t base = (size_t)wid * 64;
  for (int i = 0; i < 64; ++i) {
    size_t tau = base + i;
    int b = (int)(tau >> 16);
    int t = (int)(tau & 65535);
    const float* xb = x + ((size_t)b * 65536) * 64;
    float pm = (t > 0)     ? xb[(size_t)(t - 1) * 64 + lane] : 0.f;
    float pc =               xb[(size_t)t * 64 + lane];
    float pp = (t < 65535) ? xb[(size_t)(t + 1) * 64 + lane] : 0.f;
    float s = pm * w0 + pc * w1 + pp * w2;
    #pragma unroll
    for (int off = 32; off; off >>= 1) s += __shfl_down(s, off);
    if (lane == 0) out[tau] = s + bb;
  }
}

// ---------------- nz: per-token sum of squares ----------------------------
__global__ __launch_bounds__(256) void nz_kernel(
    const float* __restrict__ ze, float* __restrict__ nz)
{
  int lane = threadIdx.x & 63;
  int tok  = (blockIdx.x * 256 + threadIdx.x) >> 6;
  float v = ze[(size_t)tok * 64 + lane];
  float s = v * v;
  #pragma unroll
  for (int off = 32; off; off >>= 1) s += __shfl_down(s, off);
  if (lane == 0) nz[tok] = s;
}

// ---------------- vq_dots: 1 codebook row per thread, grid.y = cb half ----
#define VQA_TOKS 32
__global__ __launch_bounds__(256) void vq_dots_kernel(
    const float* __restrict__ ze, const float* __restrict__ cb,
    const float* __restrict__ nzbuf, float* __restrict__ sim_out,
    float2* __restrict__ pmin)
{
  __shared__ float zs[VQA_TOKS * 64];        // 8 KB
  const int tid = threadIdx.x;
  {
    const float4* src = (const float4*)(ze + (size_t)blockIdx.x * VQA_TOKS * 64);
    float4* dst = (float4*)zs;
    dst[tid]       = src[tid];
    dst[tid + 256] = src[tid + 256];
  }
  const int c = blockIdx.y * 256 + tid;
  float r[64];
  #pragma unroll
  for (int q = 0; q < 16; ++q) {
    float4 a = ((const float4*)cb)[(size_t)c * 16 + q];
    r[4*q] = a.x; r[4*q+1] = a.y; r[4*q+2] = a.z; r[4*q+3] = a.w;
  }
  float ne = 0.f;
  #pragma unroll
  for (int d = 0; d < 64; ++d) ne += r[d] * r[d];
  const float rsne = 1.f / sqrtf(ne);
  const int wvid = tid >> 6;
  __syncthreads();

  for (int it = 0; it < VQA_TOKS; ++it) {
    const int tok = blockIdx.x * VQA_TOKS + it;
    const float4* z4 = (const float4*)(zs + it * 64);
    float dot = 0.f;
    #pragma unroll
    for (int q = 0; q < 16; ++q) {
      float4 zv = z4[q];
      dot += zv.x * r[4*q] + zv.y * r[4*q+1] + zv.z * r[4*q+2] + zv.w * r[4*q+3];
    }
    const float nzv = nzbuf[tok];
    float dist = (-2.f * dot + nzv) + ne;
    sim_out[(size_t)tok * 512 + c] = dot * (1.f / sqrtf(nzv)) * rsne;

    float md = dist; int mi = c;
    #pragma unroll
    for (int off = 32; off; off >>= 1) {
      float od = __shfl_down(md, off);
      int   oi = __shfl_down(mi, off);
      if (od < md || (od == md && oi < mi)) { md = od; mi = oi; }
    }
    if ((tid & 63) == 0) pmin[tok * 8 + blockIdx.y * 4 + wvid] = make_float2(md, (float)mi);
  }
}

// ---------------- vq_finish: cross-partial argmin, z_q, ids, loss ---------
__global__ __launch_bounds__(256) void vq_finish_kernel(
    const float* __restrict__ ze, const float* __restrict__ cb,
    const float2* __restrict__ pmin, float* __restrict__ zq,
    float* __restrict__ ids_out, float* __restrict__ blocksum)
{
  const int tid = threadIdx.x;
  const int lane = tid & 63, wvid = tid >> 6;
  float lloss = 0.f;
  for (int it = 0; it < 16; ++it) {
    const int tok = blockIdx.x * 64 + wvid * 16 + it;
    float bd = 1e30f; int bi = 0;
    #pragma unroll
    for (int p = 0; p < 8; ++p) {
      float2 pr = pmin[tok * 8 + p];
      float d = pr.x; int i = (int)pr.y;
      if (d < bd || (d == bd && i < bi)) { bd = d; bi = i; }
    }
    float zev = ze[(size_t)tok * 64 + lane];
    float cv  = cb[(size_t)bi * 64 + lane];
    float df = zev - cv;
    float s = df * df;
    #pragma unroll
    for (int off = 32; off; off >>= 1) s += __shfl_down(s, off);
    zq[(size_t)tok * 64 + lane] = cv;
    if (lane == 0) { ids_out[tok] = (float)bi; lloss += sqrtf(s); }
  }
  __shared__ float ls[4];
  if (lane == 0) ls[wvid] = lloss;
  __syncthreads();
  if (tid == 0) blocksum[blockIdx.x] = ls[0] + ls[1] + ls[2] + ls[3];
}

__global__ void loss_fin_kernel(const float* __restrict__ blocksum,
                                float* __restrict__ out)
{
  const int lane = threadIdx.x;  // 64 threads
  float s = 0.f;
  for (int i = lane; i < 512; i += 64) s += blocksum[i];
  #pragma unroll
  for (int off = 32; off; off >>= 1) s += __shfl_down(s, off);
  if (lane == 0) out[0] = 1.25f * s / 32768.f;
}

// ---------------------------------------------------------------------------
extern "C" void kernel_launch(void* const* d_in, const int* in_sizes, int n_in,
                              void* d_out, int out_size, void* d_ws, size_t ws_size,
                              hipStream_t stream)
{
  const float* x       = (const float*)d_in[0];
  const float* w_down0 = (const float*)d_in[1];
  const float* b_down0 = (const float*)d_in[2];
  const float* w_down  = (const float*)d_in[3];
  const float* b_down  = (const float*)d_in[4];
  const float* w_res_e = (const float*)d_in[5];
  const float* b_res_e = (const float*)d_in[6];
  const float* cb      = (const float*)d_in[7];
  const float* w_res_d = (const float*)d_in[8];
  const float* b_res_d = (const float*)d_in[9];
  const float* w_up    = (const float*)d_in[10];
  const float* b_up    = (const float*)d_in[11];
  const float* w_proj  = (const float*)d_in[12];
  const float* b_proj  = (const float*)d_in[13];

  float* out = (float*)d_out;
  const size_t BUF = (size_t)4 * 65536 * 64;
  float*  bufA     = (float*)d_ws;
  float*  bufB     = bufA + BUF;
  float*  nzbuf    = bufB + BUF;
  float2* pmin     = (float2*)(nzbuf + 32768);
  float*  blocksum = (float*)(pmin + 32768 * 8);

  float* h = bufA;
  float* tmp = bufB;

  // ---- encoder ----
  down0_kernel<<<32768, 256, 0, stream>>>(x, w_down0, b_down0, h);
  int T = 32768;
  for (int blk = 0; blk < 3; ++blk) {
    if (blk > 0) {
      down2_kernel<<<dim3(T / 2 / 64, 2, 4), 256, 0, stream>>>(
          h, w_down + (size_t)(blk - 1) * 4 * 64 * 64, b_down + (blk - 1) * 64, tmp, T);
      T >>= 1;
      float* s = h; h = tmp; tmp = s;
    }
    for (int r = 0; r < 4; ++r) {
      const float* w0p = w_res_e + (((size_t)blk * 4 + r) * 2 + 0) * 3 * 64 * 64;
      const float* w1p = w_res_e + (((size_t)blk * 4 + r) * 2 + 1) * 3 * 64 * 64;
      const float* b0p = b_res_e + (((size_t)blk * 4 + r) * 2 + 0) * 64;
      const float* b1p = b_res_e + (((size_t)blk * 4 + r) * 2 + 1) * 64;
      conv3_kernel<3, false><<<dim3(T / 128, 2, 4), 256, 0, stream>>>(h, w0p, b0p, nullptr, tmp, T);
      conv3_kernel<1, true ><<<dim3(T / 128, 2, 4), 256, 0, stream>>>(tmp, w1p, b1p, h, h, T);
    }
  }

  // ---- VQ (T == 8192, z_e in h; 32768 tokens) ----
  nz_kernel<<<8192, 256, 0, stream>>>(h, nzbuf);
  vq_dots_kernel<<<dim3(32768 / VQA_TOKS, 2), 256, 0, stream>>>(h, cb, nzbuf, out + OFF_SIM, pmin);
  vq_finish_kernel<<<512, 256, 0, stream>>>(h, cb, pmin, tmp, out + OFF_IDS, blocksum);
  loss_fin_kernel<<<1, 64, 0, stream>>>(blocksum, out + OFF_LOSS);
  { float* s = h; h = tmp; tmp = s; }  // h = z_q

  // ---- decoder ----
  for (int blk = 0; blk < 3; ++blk) {
    for (int r = 0; r < 4; ++r) {
      const float* w0p = w_res_d + (((size_t)blk * 4 + r) * 2 + 0) * 3 * 64 * 64;
      const float* w1p = w_res_d + (((size_t)blk * 4 + r) * 2 + 1) * 3 * 64 * 64;
      const float* b0p = b_res_d + (((size_t)blk * 4 + r) * 2 + 0) * 64;
      const float* b1p = b_res_d + (((size_t)blk * 4 + r) * 2 + 1) * 64;
      conv3_kernel<1, false><<<dim3(T / 128, 2, 4), 256, 0, stream>>>(h, w0p, b0p, nullptr, tmp, T);
      conv3_kernel<3, true ><<<dim3(T / 128, 2, 4), 256, 0, stream>>>(tmp, w1p, b1p, h, h, T);
    }
    up_kernel<<<dim3(2 * T / 128, 2, 4), 256, 0, stream>>>(
        h, w_up + (size_t)blk * 4 * 64 * 64, b_up + blk * 64, tmp, T);
    T <<= 1;
    float* s = h; h = tmp; tmp = s;
  }

  // ---- final projection (T == 65536) ----
  proj_kernel<<<1024, 256, 0, stream>>>(h, w_proj, b_proj, out);
}